// Round 3
// baseline (609.026 us; speedup 1.0000x reference)
//
#include <hip/hip_runtime.h>
#include <hip/hip_bf16.h>
#include <stdint.h>

// Problem constants (MixtureOfLinear: B=4,S=2048,D=4096, E=8, top-2, rank 16)
#define T_TOKENS 8192
#define DIN      4096
#define DOUT     4096
#define NE       8
#define RANK     16
#define KEXT     128         // NE*RANK
#define KTOT     4224        // DIN + KEXT
#define NT       66          // KTOT / 64 K-tiles for k_main
#define SCALING  2.0f

typedef __attribute__((ext_vector_type(8)))  short  short8;   // 8 bf16 in 4 VGPRs
typedef __attribute__((ext_vector_type(4)))  float  float4v;
typedef __attribute__((ext_vector_type(16))) float  f32x16;   // 32x32 MFMA acc

__device__ __forceinline__ unsigned short f2bf(float f) {
    union { float f; unsigned int u; } c; c.f = f;
    unsigned int u = c.u;
    u += 0x7FFFu + ((u >> 16) & 1u);          // round-to-nearest-even
    return (unsigned short)(u >> 16);
}

#define GLD_LDS(g, l) __builtin_amdgcn_global_load_lds( \
    (const __attribute__((address_space(1))) void*)(g), \
    (__attribute__((address_space(3))) void*)(l), 16, 0, 0)

// ---------------------------------------------------------------------------
// Kernel 1 (merged front-end, all parts independent, no LDS, no barriers)
// ---------------------------------------------------------------------------
__global__ __launch_bounds__(256) void k_front(const float* __restrict__ x,
                                               const float* __restrict__ Wr,
                                               const float* __restrict__ Wb,
                                               const float* __restrict__ A,
                                               const float* __restrict__ Bm,
                                               unsigned short* __restrict__ xa,
                                               unsigned short* __restrict__ Wa,
                                               unsigned short* __restrict__ Acat,
                                               float* __restrict__ w8) {
    int b = blockIdx.x;
    int tid = threadIdx.x;

    if (b < 2048) {
        // ---- cast + router: token t handled by wave w ----
        int l = tid & 63, w = tid >> 6;
        int t = b * 4 + w;
        const float4* x4 = (const float4*)x;
        const float4* Wr4 = (const float4*)Wr;
        unsigned short* xarow = xa + (size_t)t * KTOT;

        float racc[NE];
#pragma unroll
        for (int e = 0; e < NE; e++) racc[e] = 0.f;

#pragma unroll 4
        for (int ci = 0; ci < 16; ci++) {           // 64 float4 / lane total
            float4 xv = x4[(size_t)t * 1024 + ci * 64 + l];
            ushort4 p;
            p.x = f2bf(xv.x); p.y = f2bf(xv.y);
            p.z = f2bf(xv.z); p.w = f2bf(xv.w);
            *(ushort4*)(xarow + (ci * 64 + l) * 4) = p;
#pragma unroll
            for (int e = 0; e < NE; e++) {
                float4 wv = Wr4[e * 1024 + ci * 64 + l];   // L2-resident
                racc[e] += xv.x * wv.x + xv.y * wv.y + xv.z * wv.z + xv.w * wv.w;
            }
        }
#pragma unroll
        for (int e = 0; e < NE; e++) {
            float v = racc[e];
#pragma unroll
            for (int off = 32; off > 0; off >>= 1) v += __shfl_xor(v, off);
            racc[e] = v;
        }
        if (l == 0) {
            int e0 = 0;
#pragma unroll
            for (int e = 1; e < NE; e++) if (racc[e] > racc[e0]) e0 = e;
            int e1 = -1;
#pragma unroll
            for (int e = 0; e < NE; e++)
                if (e != e0 && (e1 < 0 || racc[e] > racc[e1])) e1 = e;
            float a1 = __expf(racc[e1] - racc[e0]);
            float inv = 1.0f / (1.0f + a1);
            float* wrow = w8 + t * NE;
#pragma unroll
            for (int e = 0; e < NE; e++)
                wrow[e] = (e == e0) ? inv * SCALING : ((e == e1) ? a1 * inv * SCALING : 0.f);
        }
    } else if (b < 6144) {
        // ---- W_base cast: 4 float4 per thread ----
        int base = (b - 2048) * 1024 + tid;
#pragma unroll
        for (int j = 0; j < 4; j++) {
            int idx = base + j * 256;               // 0 .. 4194303
            float4 v = ((const float4*)Wb)[idx];
            int o  = idx >> 10;
            int kc = idx & 1023;
            ushort4 p;
            p.x = f2bf(v.x); p.y = f2bf(v.y); p.z = f2bf(v.z); p.w = f2bf(v.w);
            *(ushort4*)(Wa + (size_t)o * KTOT + kc * 4) = p;
        }
    } else {
        // ---- A cast + B pack, float4-vectorized ----
        int idx = (b - 6144) * 256 + tid;           // 0 .. 262143 (float4 items)
        if (idx < 131072) {
            float4 v = ((const float4*)A)[idx];
            ushort4 p;
            p.x = f2bf(v.x); p.y = f2bf(v.y); p.z = f2bf(v.z); p.w = f2bf(v.w);
            *(ushort4*)(Acat + (size_t)idx * 4) = p;
        } else {
            int j = idx - 131072;                   // 0 .. 131071
            int o = j >> 5;                         // 32 float4 per o-row
            int q = j & 31;                         // rem0 = q*4, e = q>>2
            int e = q >> 2;
            float4 v = ((const float4*)Bm)[(size_t)e * 16384 + o * 4 + (q & 3)];
            ushort4 p;
            p.x = f2bf(v.x); p.y = f2bf(v.y); p.z = f2bf(v.z); p.w = f2bf(v.w);
            *(ushort4*)(Wa + (size_t)o * KTOT + DIN + q * 4) = p;
        }
    }
}

// ---------------------------------------------------------------------------
// k_h: h[t,er] = xa_bf16[t,:4096] · Acat[er,:] * router weight ->
// xa[t, 4096+er]. M=8192 N=128 K=4096. BM=32, BK=128, 32 iters, double-
// buffered staging, counted vmcnt(10).
// ---------------------------------------------------------------------------
#define STAGEH(kt, bb) do { \
    int k0_ = (kt) * 128; \
    _Pragma("unroll") \
    for (int it_ = 0; it_ < 2; it_++) { \
        int c_ = it_ * 256 + tid; \
        int row_ = c_ >> 4, s_ = c_ & 15; \
        int kc_ = s_ ^ (row_ & 15); \
        GLD_LDS(xa + (size_t)(m0 + row_) * KTOT + k0_ + kc_ * 8, lds_x + (bb) * 4096 + c_ * 8); \
    } \
    _Pragma("unroll") \
    for (int it_ = 0; it_ < 8; it_++) { \
        int c_ = it_ * 256 + tid; \
        int row_ = c_ >> 4, s_ = c_ & 15; \
        int kc_ = s_ ^ (row_ & 15); \
        GLD_LDS(Acat + (size_t)row_ * DIN + k0_ + kc_ * 8, lds_a + (bb) * 16384 + c_ * 8); \
    } \
} while (0)

__global__ __launch_bounds__(256) void k_h(unsigned short* __restrict__ xa,
                                           const unsigned short* __restrict__ Acat,
                                           const float* __restrict__ w8) {
    __shared__ unsigned short lds_x[2 * 32 * 128];  // 16 KB (2 buf)
    __shared__ unsigned short lds_a[2 * 128 * 128]; // 64 KB (2 buf)
    int m0  = blockIdx.x * 32;
    int tid = threadIdx.x;
    int l = tid & 63, w = tid >> 6;
    int quad = l >> 4, lr = l & 15;

    float4v acc[2][2] = {};                         // [mi][ni]

    STAGEH(0, 0);
    for (int kt = 0; kt < 32; ++kt) {
        int bb = kt & 1;
        if (kt + 1 < 32) {
            STAGEH(kt + 1, bb ^ 1);
            asm volatile("s_waitcnt vmcnt(10)" ::: "memory");  // tile kt landed
        } else {
            asm volatile("s_waitcnt vmcnt(0)" ::: "memory");
        }
        __syncthreads();
        const unsigned short* lx = lds_x + bb * 4096;
        const unsigned short* la = lds_a + bb * 16384;
#pragma unroll
        for (int kk = 0; kk < 4; kk++) {
            int kc = kk * 4 + quad;
            short8 a[2], bfr[2];
#pragma unroll
            for (int mi = 0; mi < 2; mi++) {
                int row = mi * 16 + lr;
                a[mi] = *(const short8*)&lx[row * 128 + ((kc ^ lr) * 8)];
            }
#pragma unroll
            for (int ni = 0; ni < 2; ni++) {
                int row = w * 32 + ni * 16 + lr;
                bfr[ni] = *(const short8*)&la[row * 128 + ((kc ^ lr) * 8)];
            }
#pragma unroll
            for (int mi = 0; mi < 2; mi++)
#pragma unroll
                for (int ni = 0; ni < 2; ni++)
                    acc[mi][ni] = __builtin_amdgcn_mfma_f32_16x16x32_bf16(a[mi], bfr[ni], acc[mi][ni], 0, 0, 0);
        }
        __syncthreads();                            // all waves done reading bb
    }

#pragma unroll
    for (int mi = 0; mi < 2; mi++)
#pragma unroll
        for (int ni = 0; ni < 2; ni++) {
            int col = w * 32 + ni * 16 + lr;        // er index 0..127
            int e = col >> 4;
#pragma unroll
            for (int i = 0; i < 4; i++) {
                int t = m0 + mi * 16 + quad * 4 + i;
                float v = acc[mi][ni][i] * w8[t * NE + e];
                xa[(size_t)t * KTOT + DIN + col] = f2bf(v);
            }
        }
}

// ---------------------------------------------------------------------------
// Main GEMM: out[t,o] = b_base[o] + xa[t,:]·Wa[o,:], K=4224 = 66 tiles of 64.
// 256x256 tile, 8 waves (2M x 4N), wave tile 128x64 as 4x2 of 32x32 MFMA.
// TWO phases per K-tile (kq-pair each): 12 ds_read_b128 + 1 half-tile stage
// (4 gload_lds) + vmcnt(8) -> barrier -> lgkm -> 16x mfma_32x32x16 -> barrier.
// 3-deep half-tile ring: H staged 3 phases, verified 1 phase, before use.
// Barriers/K-tile: 4 (was 8). LDS layout + stage inverse-swizzle identical
// to the verified r1/r2 kernel; only read addressing + MFMA shape changed.
// Read swizzle: granule = (2*kq2 + hi) ^ ((lr>>1)&3) — 8-deep balanced,
// conflict-free (matches stored permutation chunk^((row16>>1)&3)).
// XCD chunks 8bm x 8bn (8 chunks = 8 XCDs, bijective): per-XCD K-slice
// working set 512 KB << 4 MB L2 -> FETCH ~557 -> ~420 MB.
// ---------------------------------------------------------------------------
#define READ_AB(h) do { \
    const char* pa_ = smem + buf * 32768 + (h) * 16384; \
    const char* pb_ = pa_ + 65536; \
    _Pragma("unroll") for (int mi_ = 0; mi_ < 4; mi_++) { \
        af[0][mi_] = *(const short8*)(pa_ + aoff0 + mi_ * 2048); \
        af[1][mi_] = *(const short8*)(pa_ + (aoff0 ^ 32) + mi_ * 2048); } \
    _Pragma("unroll") for (int ni_ = 0; ni_ < 2; ni_++) { \
        bfr[0][ni_] = *(const short8*)(pb_ + boff0 + ni_ * 2048); \
        bfr[1][ni_] = *(const short8*)(pb_ + (boff0 ^ 32) + ni_ * 2048); } \
} while (0)
#define MFMA_PHASE() do { \
    __builtin_amdgcn_s_setprio(1); \
    _Pragma("unroll") for (int kq_ = 0; kq_ < 2; kq_++) \
    _Pragma("unroll") for (int mi_ = 0; mi_ < 4; mi_++) \
    _Pragma("unroll") for (int ni_ = 0; ni_ < 2; ni_++) \
        acc[mi_][ni_] = __builtin_amdgcn_mfma_f32_32x32x16_bf16(af[kq_][mi_], bfr[kq_][ni_], acc[mi_][ni_], 0, 0, 0); \
    __builtin_amdgcn_s_setprio(0); \
} while (0)
#define STAGE(srcP, regbase, ts, kh, tb) do { \
    const unsigned short* s_ = (srcP) + (size_t)((ts) * 64 + (kh) * 32); \
    char* d_ = smem + (regbase) + (tb) * 32768 + (kh) * 16384 + tid16; \
    GLD_LDS(s_, d_); \
    GLD_LDS(s_ + (size_t)128 * KTOT, d_ + 8192); \
} while (0)
#define BAR() __builtin_amdgcn_s_barrier()
#define LGKM0() do { asm volatile("s_waitcnt lgkmcnt(0)" ::: "memory"); \
                     __builtin_amdgcn_sched_barrier(0); } while (0)

__global__ __launch_bounds__(512, 2) void k_main(const unsigned short* __restrict__ xa,
                                                 const unsigned short* __restrict__ Wa,
                                                 const float* __restrict__ bias,
                                                 float* __restrict__ out) {
    extern __shared__ char smem[];                  // 131072 B dynamic
    int tid = threadIdx.x;
    int l = tid & 63, w = tid >> 6;
    int lr = l & 15, quad = l >> 4;
    int wm = w >> 2, wn = w & 3;

    // XCD swizzle: 8 chunks of 8bm x 8bn, chunk c -> XCD c (bijective).
    int bid = blockIdx.x;
    int xcd = bid & 7, idx = bid >> 3;              // idx 0..63
    int bm  = (xcd & 3) * 8 + (idx & 7);            // 0..31
    int bn  = (xcd >> 2) * 8 + (idx >> 3);          // 0..15

    // ds_read side: block = (wm*8|wn*4) + sub*2 + q1; granule0 = (hi^gx)
    int q1 = quad & 1, hi = quad >> 1;
    int gx = (lr >> 1) & 3;
    int g0 = ((hi ^ gx) << 4);
    int aoff0 = (wm * 8 + q1) * 1024 + lr * 64 + g0;
    int boff0 = (wn * 4 + q1) * 1024 + lr * 64 + g0;

    // stage side (inverse swizzle on the GLOBAL source; LDS dest linear)
    int srow  = w * 16 + ((tid >> 2) & 15);
    int skq   = (tid & 3) ^ ((tid >> 3) & 3);
    int tid16 = tid * 16;
    const unsigned short* srcA = xa + (size_t)(bm * 256 + srow) * KTOT + skq * 8;
    const unsigned short* srcB = Wa + (size_t)(bn * 256 + srow) * KTOT + skq * 8;

    f32x16 acc[4][2] = {};                          // [mi][ni]
    short8 af[2][4], bfr[2][2];

    // ---- prologue: H(0,0), H(0,1), H(1,0) = 12 loads/thread
    STAGE(srcA, 0,     0, 0, 0); STAGE(srcB, 65536, 0, 0, 0);
    STAGE(srcA, 0,     0, 1, 0); STAGE(srcB, 65536, 0, 1, 0);
    STAGE(srcA, 0,     1, 0, 1); STAGE(srcB, 65536, 1, 0, 1);
    asm volatile("s_waitcnt vmcnt(8)" ::: "memory");  // H(0,0) landed
    BAR();

    for (int t = 0; t < NT; ++t) {
        int buf  = t & 1, nbuf = buf ^ 1;
        int ts1  = (t + 1 < NT) ? t + 1 : NT - 1;   // clamp: dup stage, slot dead
        int ts2  = (t + 2 < NT) ? t + 2 : NT - 1;

        // phase 1: frags of H(t,0); stage H(t+1,1)->nbuf; verify H(t,1)
        READ_AB(0);
        STAGE(srcA, 0,     ts1, 1, nbuf);
        STAGE(srcB, 65536, ts1, 1, nbuf);
        asm volatile("s_waitcnt vmcnt(8)" ::: "memory");
        BAR(); LGKM0();
        MFMA_PHASE();
        BAR();

        // phase 2: frags of H(t,1); stage H(t+2,0)->buf; verify H(t+1,0)
        READ_AB(1);
        STAGE(srcA, 0,     ts2, 0, buf);
        STAGE(srcB, 65536, ts2, 0, buf);
        asm volatile("s_waitcnt vmcnt(8)" ::: "memory");
        BAR(); LGKM0();
        MFMA_PHASE();
        BAR();
    }
    asm volatile("s_waitcnt vmcnt(0)" ::: "memory"); // drain before LDS dealloc

    // ---- epilogue: C = acc + bias (32x32 C/D: col=l&31, row=(r&3)+8*(r>>2)+4*(l>>5))
    int hi2 = l >> 5;
    int n31 = l & 31;
    int trow0 = bm * 256 + wm * 128;
    int ocol0 = bn * 256 + wn * 64;
#pragma unroll
    for (int ni = 0; ni < 2; ni++) {
        int o = ocol0 + ni * 32 + n31;
        float bb = bias[o];
#pragma unroll
        for (int mi = 0; mi < 4; mi++) {
#pragma unroll
            for (int r = 0; r < 16; r++) {
                int trow = trow0 + mi * 32 + (r & 3) + 8 * (r >> 2) + 4 * hi2;
                out[(size_t)trow * DOUT + o] = acc[mi][ni][r] + bb;
            }
        }
    }
}

// ---------------------------------------------------------------------------
extern "C" void kernel_launch(void* const* d_in, const int* in_sizes, int n_in,
                              void* d_out, int out_size, void* d_ws, size_t ws_size,
                              hipStream_t stream) {
    const float* x  = (const float*)d_in[0];   // [4,2048,4096]
    const float* Wb = (const float*)d_in[1];   // [4096,4096]
    const float* bb = (const float*)d_in[2];   // [4096]
    const float* Wr = (const float*)d_in[3];   // [8,4096]
    const float* A  = (const float*)d_in[4];   // [8,16,4096]
    const float* Bm = (const float*)d_in[5];   // [8,4096,16]
    float* out = (float*)d_out;

    char* ws = (char*)d_ws;
    unsigned short* xa   = (unsigned short*)(ws);                       // 8192*4224*2 = 69,206,016 B
    unsigned short* Wa   = (unsigned short*)(ws + 69206016);            // 4096*4224*2 = 34,603,008 B
    unsigned short* Acat = (unsigned short*)(ws + 69206016 + 34603008); // 128*4096*2  =  1,048,576 B
    float*          w8   = (float*)(ws + 69206016 + 34603008 + 1048576);// 8192*8*4    =    262,144 B
    // total: 105,119,744 B

    static bool attr_done = false;
    if (!attr_done) {
        hipFuncSetAttribute((const void*)k_main,
                            hipFuncAttributeMaxDynamicSharedMemorySize, 131072);
        attr_done = true;
    }

    k_front<<<dim3(7168),  dim3(256), 0, stream>>>(x, Wr, Wb, A, Bm, xa, Wa, Acat, w8);
    k_h    <<<dim3(256),   dim3(256), 0, stream>>>(xa, Acat, w8);
    k_main <<<dim3(512),   dim3(512), 131072, stream>>>(xa, Wa, bb, out);
}

// Round 4
// 589.997 us; speedup vs baseline: 1.0323x; 1.0323x over previous
//
#include <hip/hip_runtime.h>
#include <hip/hip_bf16.h>
#include <stdint.h>

// Problem constants (MixtureOfLinear: B=4,S=2048,D=4096, E=8, top-2, rank 16)
#define T_TOKENS 8192
#define DIN      4096
#define DOUT     4096
#define NE       8
#define RANK     16
#define KEXT     128         // NE*RANK
#define KTOT     4224        // DIN + KEXT
#define NT       66          // KTOT / 64 K-tiles for k_main
#define SCALING  2.0f

typedef __attribute__((ext_vector_type(8))) short   short8;   // 8 bf16 in 4 VGPRs
typedef __attribute__((ext_vector_type(4))) float   float4v;

__device__ __forceinline__ unsigned short f2bf(float f) {
    union { float f; unsigned int u; } c; c.f = f;
    unsigned int u = c.u;
    u += 0x7FFFu + ((u >> 16) & 1u);          // round-to-nearest-even
    return (unsigned short)(u >> 16);
}

#define GLD_LDS(g, l) __builtin_amdgcn_global_load_lds( \
    (const __attribute__((address_space(1))) void*)(g), \
    (__attribute__((address_space(3))) void*)(l), 16, 0, 0)

// ---------------------------------------------------------------------------
// Kernel 1 (merged front-end, all parts independent, no LDS, no barriers)
// ---------------------------------------------------------------------------
__global__ __launch_bounds__(256) void k_front(const float* __restrict__ x,
                                               const float* __restrict__ Wr,
                                               const float* __restrict__ Wb,
                                               const float* __restrict__ A,
                                               const float* __restrict__ Bm,
                                               unsigned short* __restrict__ xa,
                                               unsigned short* __restrict__ Wa,
                                               unsigned short* __restrict__ Acat,
                                               float* __restrict__ w8) {
    int b = blockIdx.x;
    int tid = threadIdx.x;

    if (b < 2048) {
        // ---- cast + router: token t handled by wave w ----
        int l = tid & 63, w = tid >> 6;
        int t = b * 4 + w;
        const float4* x4 = (const float4*)x;
        const float4* Wr4 = (const float4*)Wr;
        unsigned short* xarow = xa + (size_t)t * KTOT;

        float racc[NE];
#pragma unroll
        for (int e = 0; e < NE; e++) racc[e] = 0.f;

#pragma unroll 4
        for (int ci = 0; ci < 16; ci++) {           // 64 float4 / lane total
            float4 xv = x4[(size_t)t * 1024 + ci * 64 + l];
            ushort4 p;
            p.x = f2bf(xv.x); p.y = f2bf(xv.y);
            p.z = f2bf(xv.z); p.w = f2bf(xv.w);
            *(ushort4*)(xarow + (ci * 64 + l) * 4) = p;
#pragma unroll
            for (int e = 0; e < NE; e++) {
                float4 wv = Wr4[e * 1024 + ci * 64 + l];   // L2-resident
                racc[e] += xv.x * wv.x + xv.y * wv.y + xv.z * wv.z + xv.w * wv.w;
            }
        }
#pragma unroll
        for (int e = 0; e < NE; e++) {
            float v = racc[e];
#pragma unroll
            for (int off = 32; off > 0; off >>= 1) v += __shfl_xor(v, off);
            racc[e] = v;
        }
        if (l == 0) {
            int e0 = 0;
#pragma unroll
            for (int e = 1; e < NE; e++) if (racc[e] > racc[e0]) e0 = e;
            int e1 = -1;
#pragma unroll
            for (int e = 0; e < NE; e++)
                if (e != e0 && (e1 < 0 || racc[e] > racc[e1])) e1 = e;
            float a1 = __expf(racc[e1] - racc[e0]);
            float inv = 1.0f / (1.0f + a1);
            float* wrow = w8 + t * NE;
#pragma unroll
            for (int e = 0; e < NE; e++)
                wrow[e] = (e == e0) ? inv * SCALING : ((e == e1) ? a1 * inv * SCALING : 0.f);
        }
    } else if (b < 6144) {
        // ---- W_base cast: 4 float4 per thread ----
        int base = (b - 2048) * 1024 + tid;
#pragma unroll
        for (int j = 0; j < 4; j++) {
            int idx = base + j * 256;               // 0 .. 4194303
            float4 v = ((const float4*)Wb)[idx];
            int o  = idx >> 10;
            int kc = idx & 1023;
            ushort4 p;
            p.x = f2bf(v.x); p.y = f2bf(v.y); p.z = f2bf(v.z); p.w = f2bf(v.w);
            *(ushort4*)(Wa + (size_t)o * KTOT + kc * 4) = p;
        }
    } else {
        // ---- A cast + B pack, float4-vectorized ----
        int idx = (b - 6144) * 256 + tid;           // 0 .. 262143 (float4 items)
        if (idx < 131072) {
            float4 v = ((const float4*)A)[idx];
            ushort4 p;
            p.x = f2bf(v.x); p.y = f2bf(v.y); p.z = f2bf(v.z); p.w = f2bf(v.w);
            *(ushort4*)(Acat + (size_t)idx * 4) = p;
        } else {
            int j = idx - 131072;                   // 0 .. 131071
            int o = j >> 5;                         // 32 float4 per o-row
            int q = j & 31;                         // rem0 = q*4, e = q>>2
            int e = q >> 2;
            float4 v = ((const float4*)Bm)[(size_t)e * 16384 + o * 4 + (q & 3)];
            ushort4 p;
            p.x = f2bf(v.x); p.y = f2bf(v.y); p.z = f2bf(v.z); p.w = f2bf(v.w);
            *(ushort4*)(Wa + (size_t)o * KTOT + DIN + q * 4) = p;
        }
    }
}

// ---------------------------------------------------------------------------
// k_h: h[t,er] = xa_bf16[t,:4096] · Acat[er,:] * router weight ->
// xa[t, 4096+er]. M=8192 N=128 K=4096. BM=32, BK=128, 32 iters, double-
// buffered staging, counted vmcnt(10).
// ---------------------------------------------------------------------------
#define STAGEH(kt, bb) do { \
    int k0_ = (kt) * 128; \
    _Pragma("unroll") \
    for (int it_ = 0; it_ < 2; it_++) { \
        int c_ = it_ * 256 + tid; \
        int row_ = c_ >> 4, s_ = c_ & 15; \
        int kc_ = s_ ^ (row_ & 15); \
        GLD_LDS(xa + (size_t)(m0 + row_) * KTOT + k0_ + kc_ * 8, lds_x + (bb) * 4096 + c_ * 8); \
    } \
    _Pragma("unroll") \
    for (int it_ = 0; it_ < 8; it_++) { \
        int c_ = it_ * 256 + tid; \
        int row_ = c_ >> 4, s_ = c_ & 15; \
        int kc_ = s_ ^ (row_ & 15); \
        GLD_LDS(Acat + (size_t)row_ * DIN + k0_ + kc_ * 8, lds_a + (bb) * 16384 + c_ * 8); \
    } \
} while (0)

__global__ __launch_bounds__(256) void k_h(unsigned short* __restrict__ xa,
                                           const unsigned short* __restrict__ Acat,
                                           const float* __restrict__ w8) {
    __shared__ unsigned short lds_x[2 * 32 * 128];  // 16 KB (2 buf)
    __shared__ unsigned short lds_a[2 * 128 * 128]; // 64 KB (2 buf)
    int m0  = blockIdx.x * 32;
    int tid = threadIdx.x;
    int l = tid & 63, w = tid >> 6;
    int quad = l >> 4, lr = l & 15;

    float4v acc[2][2] = {};                         // [mi][ni]

    STAGEH(0, 0);
    for (int kt = 0; kt < 32; ++kt) {
        int bb = kt & 1;
        if (kt + 1 < 32) {
            STAGEH(kt + 1, bb ^ 1);
            asm volatile("s_waitcnt vmcnt(10)" ::: "memory");  // tile kt landed
        } else {
            asm volatile("s_waitcnt vmcnt(0)" ::: "memory");
        }
        __syncthreads();
        const unsigned short* lx = lds_x + bb * 4096;
        const unsigned short* la = lds_a + bb * 16384;
#pragma unroll
        for (int kk = 0; kk < 4; kk++) {
            int kc = kk * 4 + quad;
            short8 a[2], bfr[2];
#pragma unroll
            for (int mi = 0; mi < 2; mi++) {
                int row = mi * 16 + lr;
                a[mi] = *(const short8*)&lx[row * 128 + ((kc ^ lr) * 8)];
            }
#pragma unroll
            for (int ni = 0; ni < 2; ni++) {
                int row = w * 32 + ni * 16 + lr;
                bfr[ni] = *(const short8*)&la[row * 128 + ((kc ^ lr) * 8)];
            }
#pragma unroll
            for (int mi = 0; mi < 2; mi++)
#pragma unroll
                for (int ni = 0; ni < 2; ni++)
                    acc[mi][ni] = __builtin_amdgcn_mfma_f32_16x16x32_bf16(a[mi], bfr[ni], acc[mi][ni], 0, 0, 0);
        }
        __syncthreads();                            // all waves done reading bb
    }

#pragma unroll
    for (int mi = 0; mi < 2; mi++)
#pragma unroll
        for (int ni = 0; ni < 2; ni++) {
            int col = w * 32 + ni * 16 + lr;        // er index 0..127
            int e = col >> 4;
#pragma unroll
            for (int i = 0; i < 4; i++) {
                int t = m0 + mi * 16 + quad * 4 + i;
                float v = acc[mi][ni][i] * w8[t * NE + e];
                xa[(size_t)t * KTOT + DIN + col] = f2bf(v);
            }
        }
}

// ---------------------------------------------------------------------------
// Main GEMM: out[t,o] = b_base[o] + xa[t,:]·Wa[o,:], K=4224 = 66 tiles of 64.
// 256x256 tile, 8 waves (2M x 4N), 4 phases per K-tile — the r2 structure
// (verified: bank conflicts 0, 1042 TF) with ONE change: 2D XCD chunk
// mapping (verified in r3: FETCH 557 -> 203 MB). Each XCD owns an 8bm x 8bn
// chunk; per-K-slice working set ~2.2 MB < 4 MB L2.
// ---------------------------------------------------------------------------
#define LOADA(dst, basep, mlo) { \
    _Pragma("unroll") for (int i_ = 0; i_ < 4; i_++) \
        dst[i_] = *(const short8*)((basep) + aoff + ((mlo) + i_) * 1024); }
#define LOADB(dst, basep) { \
    _Pragma("unroll") for (int i_ = 0; i_ < 4; i_++) \
        dst[i_] = *(const short8*)((basep) + boff + i_ * 1024); }
#define MFMA44(mlo) { \
    __builtin_amdgcn_s_setprio(1); \
    _Pragma("unroll") for (int i_ = 0; i_ < 4; i_++) \
    _Pragma("unroll") for (int j_ = 0; j_ < 4; j_++) \
        acc[(mlo) + i_][j_] = __builtin_amdgcn_mfma_f32_16x16x32_bf16(af[i_], bf[j_], acc[(mlo) + i_][j_], 0, 0, 0); \
    __builtin_amdgcn_s_setprio(0); }
#define STAGE(srcP, regbase, ts, kh, tb) do { \
    const unsigned short* s_ = (srcP) + (size_t)((ts) * 64 + (kh) * 32); \
    char* d_ = smem + (regbase) + (tb) * 32768 + (kh) * 16384 + tid16; \
    GLD_LDS(s_, d_); \
    GLD_LDS(s_ + (size_t)128 * KTOT, d_ + 8192); \
} while (0)
#define BAR() __builtin_amdgcn_s_barrier()
#define LGKM0() do { asm volatile("s_waitcnt lgkmcnt(0)" ::: "memory"); \
                     __builtin_amdgcn_sched_barrier(0); } while (0)

__global__ __launch_bounds__(512, 2) void k_main(const unsigned short* __restrict__ xa,
                                                 const unsigned short* __restrict__ Wa,
                                                 const float* __restrict__ bias,
                                                 float* __restrict__ out) {
    extern __shared__ char smem[];                  // 131072 B dynamic
    int tid = threadIdx.x;
    int l = tid & 63, w = tid >> 6;
    int lr = l & 15, quad = l >> 4;
    int wm = w >> 2, wn = w & 3;

    // 2D XCD chunk swizzle (r3-verified): chunk c -> XCD c, 8bm x 8bn each.
    int bid = blockIdx.x;
    int xcd = bid & 7, idx = bid >> 3;              // idx 0..63
    int bm  = (xcd & 3) * 8 + (idx & 7);            // 0..31
    int bn  = (xcd >> 2) * 8 + (idx >> 3);          // 0..15

    // ds_read side of the swizzle (r2-verified conflict-free)
    int laneoff = (lr * 4 + (quad ^ ((lr >> 1) & 3))) * 16;   // bytes in 1KB block
    int aoff = wm * 8192 + laneoff;                 // A: 16-row block = wm*8+mi
    int boff = wn * 4096 + laneoff;                 // B: 16-row block = wn*4+ni

    // stage side (inverse swizzle on the GLOBAL source; LDS dest linear)
    int srow  = w * 16 + ((tid >> 2) & 15);         // it=0 rows 0..127 (+128 for it=1)
    int skq   = (tid & 3) ^ ((tid >> 3) & 3);
    int tid16 = tid * 16;
    const unsigned short* srcA = xa + (size_t)(bm * 256 + srow) * KTOT + skq * 8;
    const unsigned short* srcB = Wa + (size_t)(bn * 256 + srow) * KTOT + skq * 8;

    float4v acc[8][4] = {};                         // [mi 0..7][ni 0..3]
    short8 af[4], bf[4];

    // ---- prologue: tile0 (all 4 regions) + tile1 k-half0 = 12 loads/thread
    STAGE(srcA, 0,     0, 0, 0);
    STAGE(srcB, 65536, 0, 0, 0);
    STAGE(srcA, 0,     0, 1, 0);
    STAGE(srcB, 65536, 0, 1, 0);
    STAGE(srcA, 0,     1, 0, 1);
    STAGE(srcB, 65536, 1, 0, 1);
    asm volatile("s_waitcnt vmcnt(4)" ::: "memory");  // tile0 landed; t1k0 in flight
    BAR();

    for (int t = 0; t < NT; ++t) {
        int buf  = t & 1, nbuf = buf ^ 1;
        int ts1  = (t + 1 < NT) ? t + 1 : NT - 1;   // clamp: dup stage, slot dead
        int ts2  = (t + 2 < NT) ? t + 2 : NT - 1;
        const char* pa = smem + buf * 32768;          // A kh0 (kh1 at +16384)
        const char* pb = smem + 65536 + buf * 32768;  // B kh0

        // phase 1: A mi0-3 kh0 + B kh0 (8 reads); stage A(t+1,k1)->nbuf
        LOADA(af, pa, 0);
        LOADB(bf, pb);
        STAGE(srcA, 0, ts1, 1, nbuf);
        BAR(); LGKM0();
        MFMA44(0);
        BAR();

        // phase 2: A mi4-7 kh0 (4 reads, bf reused); stage B(t+1,k1)->nbuf
        LOADA(af, pa, 4);
        STAGE(srcB, 65536, ts1, 1, nbuf);
        BAR(); LGKM0();
        MFMA44(4);
        BAR();

        // phase 3: A mi0-3 kh1 + B kh1 (8 reads); stage A(t+2,k0)->buf
        LOADA(af, pa + 16384, 0);
        LOADB(bf, pb + 16384);
        STAGE(srcA, 0, ts2, 0, buf);
        BAR(); LGKM0();
        MFMA44(0);
        BAR();

        // phase 4: A mi4-7 kh1; stage B(t+2,k0)->buf; ONE counted wait:
        // 12 outstanding -> vmcnt(4) drains tile t+1 fully, leaves t+2 k0.
        LOADA(af, pa + 16384, 4);
        STAGE(srcB, 65536, ts2, 0, buf);
        asm volatile("s_waitcnt vmcnt(4)" ::: "memory");
        BAR(); LGKM0();
        MFMA44(4);
        BAR();
    }
    asm volatile("s_waitcnt vmcnt(0)" ::: "memory"); // drain before LDS dealloc

    // ---- epilogue: C = acc + bias
    int trow0 = bm * 256 + wm * 128;
    int ocol0 = bn * 256 + wn * 64;
#pragma unroll
    for (int ni = 0; ni < 4; ni++) {
        int o = ocol0 + ni * 16 + lr;
        float bb = bias[o];
#pragma unroll
        for (int mi = 0; mi < 8; mi++) {
#pragma unroll
            for (int i = 0; i < 4; i++) {
                int trow = trow0 + mi * 16 + quad * 4 + i;
                out[(size_t)trow * DOUT + o] = acc[mi][ni][i] + bb;
            }
        }
    }
}

// ---------------------------------------------------------------------------
extern "C" void kernel_launch(void* const* d_in, const int* in_sizes, int n_in,
                              void* d_out, int out_size, void* d_ws, size_t ws_size,
                              hipStream_t stream) {
    const float* x  = (const float*)d_in[0];   // [4,2048,4096]
    const float* Wb = (const float*)d_in[1];   // [4096,4096]
    const float* bb = (const float*)d_in[2];   // [4096]
    const float* Wr = (const float*)d_in[3];   // [8,4096]
    const float* A  = (const float*)d_in[4];   // [8,16,4096]
    const float* Bm = (const float*)d_in[5];   // [8,4096,16]
    float* out = (float*)d_out;

    char* ws = (char*)d_ws;
    unsigned short* xa   = (unsigned short*)(ws);                       // 8192*4224*2 = 69,206,016 B
    unsigned short* Wa   = (unsigned short*)(ws + 69206016);            // 4096*4224*2 = 34,603,008 B
    unsigned short* Acat = (unsigned short*)(ws + 69206016 + 34603008); // 128*4096*2  =  1,048,576 B
    float*          w8   = (float*)(ws + 69206016 + 34603008 + 1048576);// 8192*8*4    =    262,144 B
    // total: 105,119,744 B

    static bool attr_done = false;
    if (!attr_done) {
        hipFuncSetAttribute((const void*)k_main,
                            hipFuncAttributeMaxDynamicSharedMemorySize, 131072);
        attr_done = true;
    }

    k_front<<<dim3(7168),  dim3(256), 0, stream>>>(x, Wr, Wb, A, Bm, xa, Wa, Acat, w8);
    k_h    <<<dim3(256),   dim3(256), 0, stream>>>(xa, Acat, w8);
    k_main <<<dim3(512),   dim3(512), 131072, stream>>>(xa, Wa, bb, out);
}

// Round 5
// 584.337 us; speedup vs baseline: 1.0423x; 1.0097x over previous
//
#include <hip/hip_runtime.h>
#include <hip/hip_bf16.h>
#include <stdint.h>

// Problem constants (MixtureOfLinear: B=4,S=2048,D=4096, E=8, top-2, rank 16)
#define T_TOKENS 8192
#define DIN      4096
#define DOUT     4096
#define NE       8
#define RANK     16
#define KEXT     128         // NE*RANK
#define KTOT     4224        // DIN + KEXT
#define NT       66          // KTOT / 64 K-tiles for k_main
#define SCALING  2.0f

typedef __attribute__((ext_vector_type(8))) short   short8;   // 8 bf16 in 4 VGPRs
typedef __attribute__((ext_vector_type(4))) float   float4v;

__device__ __forceinline__ unsigned short f2bf(float f) {
    union { float f; unsigned int u; } c; c.f = f;
    unsigned int u = c.u;
    u += 0x7FFFu + ((u >> 16) & 1u);          // round-to-nearest-even
    return (unsigned short)(u >> 16);
}

#define GLD_LDS(g, l) __builtin_amdgcn_global_load_lds( \
    (const __attribute__((address_space(1))) void*)(g), \
    (__attribute__((address_space(3))) void*)(l), 16, 0, 0)

// ---------------------------------------------------------------------------
// Kernel 1 (merged front-end, all parts independent, no LDS, no barriers)
// ---------------------------------------------------------------------------
__global__ __launch_bounds__(256) void k_front(const float* __restrict__ x,
                                               const float* __restrict__ Wr,
                                               const float* __restrict__ Wb,
                                               const float* __restrict__ A,
                                               const float* __restrict__ Bm,
                                               unsigned short* __restrict__ xa,
                                               unsigned short* __restrict__ Wa,
                                               unsigned short* __restrict__ Acat,
                                               float* __restrict__ w8) {
    int b = blockIdx.x;
    int tid = threadIdx.x;

    if (b < 2048) {
        // ---- cast + router: token t handled by wave w ----
        int l = tid & 63, w = tid >> 6;
        int t = b * 4 + w;
        const float4* x4 = (const float4*)x;
        const float4* Wr4 = (const float4*)Wr;
        unsigned short* xarow = xa + (size_t)t * KTOT;

        float racc[NE];
#pragma unroll
        for (int e = 0; e < NE; e++) racc[e] = 0.f;

#pragma unroll 4
        for (int ci = 0; ci < 16; ci++) {           // 64 float4 / lane total
            float4 xv = x4[(size_t)t * 1024 + ci * 64 + l];
            ushort4 p;
            p.x = f2bf(xv.x); p.y = f2bf(xv.y);
            p.z = f2bf(xv.z); p.w = f2bf(xv.w);
            *(ushort4*)(xarow + (ci * 64 + l) * 4) = p;
#pragma unroll
            for (int e = 0; e < NE; e++) {
                float4 wv = Wr4[e * 1024 + ci * 64 + l];   // L2-resident
                racc[e] += xv.x * wv.x + xv.y * wv.y + xv.z * wv.z + xv.w * wv.w;
            }
        }
#pragma unroll
        for (int e = 0; e < NE; e++) {
            float v = racc[e];
#pragma unroll
            for (int off = 32; off > 0; off >>= 1) v += __shfl_xor(v, off);
            racc[e] = v;
        }
        if (l == 0) {
            int e0 = 0;
#pragma unroll
            for (int e = 1; e < NE; e++) if (racc[e] > racc[e0]) e0 = e;
            int e1 = -1;
#pragma unroll
            for (int e = 0; e < NE; e++)
                if (e != e0 && (e1 < 0 || racc[e] > racc[e1])) e1 = e;
            float a1 = __expf(racc[e1] - racc[e0]);
            float inv = 1.0f / (1.0f + a1);
            float* wrow = w8 + t * NE;
#pragma unroll
            for (int e = 0; e < NE; e++)
                wrow[e] = (e == e0) ? inv * SCALING : ((e == e1) ? a1 * inv * SCALING : 0.f);
        }
    } else if (b < 6144) {
        // ---- W_base cast: 4 float4 per thread ----
        int base = (b - 2048) * 1024 + tid;
#pragma unroll
        for (int j = 0; j < 4; j++) {
            int idx = base + j * 256;               // 0 .. 4194303
            float4 v = ((const float4*)Wb)[idx];
            int o  = idx >> 10;
            int kc = idx & 1023;
            ushort4 p;
            p.x = f2bf(v.x); p.y = f2bf(v.y); p.z = f2bf(v.z); p.w = f2bf(v.w);
            *(ushort4*)(Wa + (size_t)o * KTOT + kc * 4) = p;
        }
    } else {
        // ---- A cast + B pack, float4-vectorized ----
        int idx = (b - 6144) * 256 + tid;           // 0 .. 262143 (float4 items)
        if (idx < 131072) {
            float4 v = ((const float4*)A)[idx];
            ushort4 p;
            p.x = f2bf(v.x); p.y = f2bf(v.y); p.z = f2bf(v.z); p.w = f2bf(v.w);
            *(ushort4*)(Acat + (size_t)idx * 4) = p;
        } else {
            int j = idx - 131072;                   // 0 .. 131071
            int o = j >> 5;                         // 32 float4 per o-row
            int q = j & 31;                         // rem0 = q*4, e = q>>2
            int e = q >> 2;
            float4 v = ((const float4*)Bm)[(size_t)e * 16384 + o * 4 + (q & 3)];
            ushort4 p;
            p.x = f2bf(v.x); p.y = f2bf(v.y); p.z = f2bf(v.z); p.w = f2bf(v.w);
            *(ushort4*)(Wa + (size_t)o * KTOT + DIN + q * 4) = p;
        }
    }
}

// ---------------------------------------------------------------------------
// k_h: h[t,er] = xa_bf16[t,:4096] · Acat[er,:] * router weight ->
// xa[t, 4096+er]. M=8192 N=128 K=4096. BM=32, BK=128, 32 iters, double-
// buffered staging, counted vmcnt(10).
// ---------------------------------------------------------------------------
#define STAGEH(kt, bb) do { \
    int k0_ = (kt) * 128; \
    _Pragma("unroll") \
    for (int it_ = 0; it_ < 2; it_++) { \
        int c_ = it_ * 256 + tid; \
        int row_ = c_ >> 4, s_ = c_ & 15; \
        int kc_ = s_ ^ (row_ & 15); \
        GLD_LDS(xa + (size_t)(m0 + row_) * KTOT + k0_ + kc_ * 8, lds_x + (bb) * 4096 + c_ * 8); \
    } \
    _Pragma("unroll") \
    for (int it_ = 0; it_ < 8; it_++) { \
        int c_ = it_ * 256 + tid; \
        int row_ = c_ >> 4, s_ = c_ & 15; \
        int kc_ = s_ ^ (row_ & 15); \
        GLD_LDS(Acat + (size_t)row_ * DIN + k0_ + kc_ * 8, lds_a + (bb) * 16384 + c_ * 8); \
    } \
} while (0)

__global__ __launch_bounds__(256) void k_h(unsigned short* __restrict__ xa,
                                           const unsigned short* __restrict__ Acat,
                                           const float* __restrict__ w8) {
    __shared__ unsigned short lds_x[2 * 32 * 128];  // 16 KB (2 buf)
    __shared__ unsigned short lds_a[2 * 128 * 128]; // 64 KB (2 buf)
    int m0  = blockIdx.x * 32;
    int tid = threadIdx.x;
    int l = tid & 63, w = tid >> 6;
    int quad = l >> 4, lr = l & 15;

    float4v acc[2][2] = {};                         // [mi][ni]

    STAGEH(0, 0);
    for (int kt = 0; kt < 32; ++kt) {
        int bb = kt & 1;
        if (kt + 1 < 32) {
            STAGEH(kt + 1, bb ^ 1);
            asm volatile("s_waitcnt vmcnt(10)" ::: "memory");  // tile kt landed
        } else {
            asm volatile("s_waitcnt vmcnt(0)" ::: "memory");
        }
        __syncthreads();
        const unsigned short* lx = lds_x + bb * 4096;
        const unsigned short* la = lds_a + bb * 16384;
#pragma unroll
        for (int kk = 0; kk < 4; kk++) {
            int kc = kk * 4 + quad;
            short8 a[2], bfr[2];
#pragma unroll
            for (int mi = 0; mi < 2; mi++) {
                int row = mi * 16 + lr;
                a[mi] = *(const short8*)&lx[row * 128 + ((kc ^ lr) * 8)];
            }
#pragma unroll
            for (int ni = 0; ni < 2; ni++) {
                int row = w * 32 + ni * 16 + lr;
                bfr[ni] = *(const short8*)&la[row * 128 + ((kc ^ lr) * 8)];
            }
#pragma unroll
            for (int mi = 0; mi < 2; mi++)
#pragma unroll
                for (int ni = 0; ni < 2; ni++)
                    acc[mi][ni] = __builtin_amdgcn_mfma_f32_16x16x32_bf16(a[mi], bfr[ni], acc[mi][ni], 0, 0, 0);
        }
        __syncthreads();                            // all waves done reading bb
    }

#pragma unroll
    for (int mi = 0; mi < 2; mi++)
#pragma unroll
        for (int ni = 0; ni < 2; ni++) {
            int col = w * 32 + ni * 16 + lr;        // er index 0..127
            int e = col >> 4;
#pragma unroll
            for (int i = 0; i < 4; i++) {
                int t = m0 + mi * 16 + quad * 4 + i;
                float v = acc[mi][ni][i] * w8[t * NE + e];
                xa[(size_t)t * KTOT + DIN + col] = f2bf(v);
            }
        }
}

// ---------------------------------------------------------------------------
// Main GEMM: out[t,o] = b_base[o] + xa[t,:]·Wa[o,:], K=4224 = 66 tiles of 64.
// 256x256 tile, 8 waves (2M x 4N), 4 phases per K-tile.
// r4 skeleton (stages / vmcnt(4) ring / barriers / 2D XCD map / swizzle all
// identical) + SOFTWARE-PIPELINED REGISTER LOADS: each phase's ds_reads are
// issued one phase EARLY into ping-pong register sets (afA/afB, bfA/bfB) and
// synchronized with COUNTED lgkmcnt — the LDS drain overlaps the previous
// phase's MFMA instead of serializing.
//   ph1: [issue afB<-A(t,kh0,mi4-7) | stage A(t+1,kh1)->nbuf] BAR lgkm(4)
//        MFMA(afA,bfA)->acc[0..3] BAR
//   ph2: [issue afA<-A(t,kh1,mi0-3)+bfB<-B(t,kh1) | stage B(t+1,kh1)] BAR
//        lgkm(8) MFMA(afB,bfA)->acc[4..7] BAR
//   ph3: [issue afB<-A(t,kh1,mi4-7) | stage A(t+2,kh0)->buf] BAR lgkm(4)
//        MFMA(afA,bfB)->acc[0..3] BAR
//   ph4: stage B(t+2,kh0)->buf; vmcnt(4); BAR; issue afA,bfA<-kh0(t+1) from
//        nbuf (AFTER the vmcnt+BAR: staged-data RAW; in-flight loads target
//        buf, disjoint); lgkm(8) MFMA(afB,bfB)->acc[4..7] BAR
// Hazard ledger: reg WAR (each set reloaded >=1 phase after last consumer);
// LDS WAR (kh0 reads done by ph2 wait+BAR before ph3 stage overwrites kh0;
// nbuf kh1 reads done by prev ph4 wait before ph1/2 stages); counted waits
// {4,8,4,8} = exactly the just-issued reads outstanding.
// ---------------------------------------------------------------------------
#define LOADA4(dst, basep, mlo) { \
    _Pragma("unroll") for (int i_ = 0; i_ < 4; i_++) \
        dst[i_] = *(const short8*)((basep) + aoff + ((mlo) + i_) * 1024); }
#define LOADB4(dst, basep) { \
    _Pragma("unroll") for (int i_ = 0; i_ < 4; i_++) \
        dst[i_] = *(const short8*)((basep) + boff + i_ * 1024); }
#define MFMA44V(A_, B_, mlo) { \
    __builtin_amdgcn_s_setprio(1); \
    _Pragma("unroll") for (int i_ = 0; i_ < 4; i_++) \
    _Pragma("unroll") for (int j_ = 0; j_ < 4; j_++) \
        acc[(mlo) + i_][j_] = __builtin_amdgcn_mfma_f32_16x16x32_bf16(A_[i_], B_[j_], acc[(mlo) + i_][j_], 0, 0, 0); \
    __builtin_amdgcn_s_setprio(0); }
#define STAGE(srcP, regbase, ts, kh, tb) do { \
    const unsigned short* s_ = (srcP) + (size_t)((ts) * 64 + (kh) * 32); \
    char* d_ = smem + (regbase) + (tb) * 32768 + (kh) * 16384 + tid16; \
    GLD_LDS(s_, d_); \
    GLD_LDS(s_ + (size_t)128 * KTOT, d_ + 8192); \
} while (0)
#define BAR() __builtin_amdgcn_s_barrier()
#define LGKMC(n) do { asm volatile("s_waitcnt lgkmcnt(" #n ")" ::: "memory"); \
                      __builtin_amdgcn_sched_barrier(0); } while (0)

__global__ __launch_bounds__(512, 2) void k_main(const unsigned short* __restrict__ xa,
                                                 const unsigned short* __restrict__ Wa,
                                                 const float* __restrict__ bias,
                                                 float* __restrict__ out) {
    extern __shared__ char smem[];                  // 131072 B dynamic
    int tid = threadIdx.x;
    int l = tid & 63, w = tid >> 6;
    int lr = l & 15, quad = l >> 4;
    int wm = w >> 2, wn = w & 3;

    // 2D XCD chunk swizzle (r3/r4-verified): chunk c -> XCD c, 8bm x 8bn.
    int bid = blockIdx.x;
    int xcd = bid & 7, idx = bid >> 3;              // idx 0..63
    int bm  = (xcd & 3) * 8 + (idx & 7);            // 0..31
    int bn  = (xcd >> 2) * 8 + (idx >> 3);          // 0..15

    // ds_read side of the swizzle (r2/r4-verified conflict-free)
    int laneoff = (lr * 4 + (quad ^ ((lr >> 1) & 3))) * 16;   // bytes in 1KB block
    int aoff = wm * 8192 + laneoff;                 // A: 16-row block = wm*8+mi
    int boff = wn * 4096 + laneoff;                 // B: 16-row block = wn*4+ni

    // stage side (inverse swizzle on the GLOBAL source; LDS dest linear)
    int srow  = w * 16 + ((tid >> 2) & 15);         // it=0 rows 0..127 (+128 for it=1)
    int skq   = (tid & 3) ^ ((tid >> 3) & 3);
    int tid16 = tid * 16;
    const unsigned short* srcA = xa + (size_t)(bm * 256 + srow) * KTOT + skq * 8;
    const unsigned short* srcB = Wa + (size_t)(bn * 256 + srow) * KTOT + skq * 8;

    float4v acc[8][4] = {};                         // [mi 0..7][ni 0..3]
    short8 afA[4], afB[4], bfA[4], bfB[4];          // ping-pong operand sets

    // ---- prologue: tile0 (all 4 regions) + tile1 k-half0 = 12 loads/thread
    STAGE(srcA, 0,     0, 0, 0);
    STAGE(srcB, 65536, 0, 0, 0);
    STAGE(srcA, 0,     0, 1, 0);
    STAGE(srcB, 65536, 0, 1, 0);
    STAGE(srcA, 0,     1, 0, 1);
    STAGE(srcB, 65536, 1, 0, 1);
    asm volatile("s_waitcnt vmcnt(4)" ::: "memory");  // tile0 landed; t1k0 in flight
    BAR();
    // preload t=0 ph1 operands (kh0, buf0)
    LOADA4(afA, smem, 0);
    LOADB4(bfA, smem + 65536);

    for (int t = 0; t < NT; ++t) {
        int buf  = t & 1, nbuf = buf ^ 1;
        int ts1  = (t + 1 < NT) ? t + 1 : NT - 1;   // clamp: dup stage, slot dead
        int ts2  = (t + 2 < NT) ? t + 2 : NT - 1;
        const char* pa  = smem + buf * 32768;          // A(t) kh0 (kh1 at +16384)
        const char* pb  = smem + 65536 + buf * 32768;  // B(t) kh0
        const char* pan = smem + nbuf * 32768;         // A(t+1) kh0
        const char* pbn = smem + 65536 + nbuf * 32768; // B(t+1) kh0

        // ph1: issue afB<-A(t,kh0,mi4-7); stage A(t+1,kh1)->nbuf;
        //      MFMA on afA,bfA (loaded prev ph4 slot)
        LOADA4(afB, pa, 4);
        STAGE(srcA, 0, ts1, 1, nbuf);
        BAR(); LGKMC(4);
        MFMA44V(afA, bfA, 0);
        BAR();

        // ph2: issue afA<-A(t,kh1,mi0-3) + bfB<-B(t,kh1); stage B(t+1,kh1)
        LOADA4(afA, pa + 16384, 0);
        LOADB4(bfB, pb + 16384);
        STAGE(srcB, 65536, ts1, 1, nbuf);
        BAR(); LGKMC(8);
        MFMA44V(afB, bfA, 4);
        BAR();

        // ph3: issue afB<-A(t,kh1,mi4-7); stage A(t+2,kh0)->buf
        //      (kh0 reads finished by ph2's wait + barrier)
        LOADA4(afB, pa + 16384, 4);
        STAGE(srcA, 0, ts2, 0, buf);
        BAR(); LGKMC(4);
        MFMA44V(afA, bfB, 0);
        BAR();

        // ph4: stage B(t+2,kh0)->buf; ONE counted vmcnt (12 -> 4: drains all
        // of tile t+1, leaves t+2 kh0 in flight, targeting buf); THEN issue
        // next tile's ph1 operands from nbuf (disjoint from in-flight writes)
        STAGE(srcB, 65536, ts2, 0, buf);
        asm volatile("s_waitcnt vmcnt(4)" ::: "memory");
        BAR();
        LOADA4(afA, pan, 0);
        LOADB4(bfA, pbn);
        LGKMC(8);
        MFMA44V(afB, bfB, 4);
        BAR();
    }
    asm volatile("s_waitcnt vmcnt(0) lgkmcnt(0)" ::: "memory"); // drain

    // ---- epilogue: C = acc + bias
    int trow0 = bm * 256 + wm * 128;
    int ocol0 = bn * 256 + wn * 64;
#pragma unroll
    for (int ni = 0; ni < 4; ni++) {
        int o = ocol0 + ni * 16 + lr;
        float bb = bias[o];
#pragma unroll
        for (int mi = 0; mi < 8; mi++) {
#pragma unroll
            for (int i = 0; i < 4; i++) {
                int trow = trow0 + mi * 16 + quad * 4 + i;
                out[(size_t)trow * DOUT + o] = acc[mi][ni][i] + bb;
            }
        }
    }
}

// ---------------------------------------------------------------------------
extern "C" void kernel_launch(void* const* d_in, const int* in_sizes, int n_in,
                              void* d_out, int out_size, void* d_ws, size_t ws_size,
                              hipStream_t stream) {
    const float* x  = (const float*)d_in[0];   // [4,2048,4096]
    const float* Wb = (const float*)d_in[1];   // [4096,4096]
    const float* bb = (const float*)d_in[2];   // [4096]
    const float* Wr = (const float*)d_in[3];   // [8,4096]
    const float* A  = (const float*)d_in[4];   // [8,16,4096]
    const float* Bm = (const float*)d_in[5];   // [8,4096,16]
    float* out = (float*)d_out;

    char* ws = (char*)d_ws;
    unsigned short* xa   = (unsigned short*)(ws);                       // 8192*4224*2 = 69,206,016 B
    unsigned short* Wa   = (unsigned short*)(ws + 69206016);            // 4096*4224*2 = 34,603,008 B
    unsigned short* Acat = (unsigned short*)(ws + 69206016 + 34603008); // 128*4096*2  =  1,048,576 B
    float*          w8   = (float*)(ws + 69206016 + 34603008 + 1048576);// 8192*8*4    =    262,144 B
    // total: 105,119,744 B

    static bool attr_done = false;
    if (!attr_done) {
        hipFuncSetAttribute((const void*)k_main,
                            hipFuncAttributeMaxDynamicSharedMemorySize, 131072);
        attr_done = true;
    }

    k_front<<<dim3(7168),  dim3(256), 0, stream>>>(x, Wr, Wb, A, Bm, xa, Wa, Acat, w8);
    k_h    <<<dim3(256),   dim3(256), 0, stream>>>(xa, Acat, w8);
    k_main <<<dim3(512),   dim3(512), 131072, stream>>>(xa, Wa, bb, out);
}